// Round 2
// baseline (40.242 us; speedup 1.0000x reference)
//
#include <hip/hip_runtime.h>

#define N2 128
#define BLOCK 256

// comparison guard band: 1 +/- 2^-20 (covers <=1ulp rounding of each cross
// product plus the <=1ulp spacing at which two rounded quotients can tie)
#define ONE_P 1.00000095367431640625f
#define ONE_M 0.99999904632568359375f

__global__ __launch_bounds__(BLOCK) void matcher_kernel(
    const float4* __restrict__ boxes1,
    const float4* __restrict__ boxes2,
    float* __restrict__ out_vals,
    float* __restrict__ out_idx,
    float* __restrict__ out_labels,
    int n1)
{
#pragma clang fp contract(off)
    __shared__ float4 s_b2[N2];
    __shared__ float s_area2[N2];

    const int t = threadIdx.x;
    if (t < N2) {
        float4 b = boxes2[t];           // (y1, x1, y2, x2)
        s_b2[t] = b;
        s_area2[t] = (b.z - b.x) * (b.w - b.y);
    }
    __syncthreads();

    const int i = blockIdx.x * BLOCK + t;
    if (i >= n1) return;

    const float4 a = boxes1[i];
    const float area1 = (a.z - a.x) * (a.w - a.y);

    // two independent argmax streams (j in [0,64) and [64,128)) for ILP.
    // best kept as fraction (bi = inter, bu = clamped union); init bi=-1 so
    // the first candidate always wins (matches reference taking q_0 first).
    float biA = -1.0f, buA = 1.0f; int bxA = 0;
    float biB = -1.0f, buB = 1.0f; int bxB = 64;
    bool slow = false;

#define FRAC(J, INTER, UM)                                            \
    {                                                                 \
        const float4 b = s_b2[(J)];                                   \
        const float iy1 = fmaxf(a.x, b.x);                            \
        const float ix1 = fmaxf(a.y, b.y);                            \
        const float iy2 = fminf(a.z, b.z);                            \
        const float ix2 = fminf(a.w, b.w);                            \
        const float hy = fmaxf(iy2 - iy1, 0.0f);                      \
        const float hx = fmaxf(ix2 - ix1, 0.0f);                      \
        INTER = hy * hx;                                              \
        UM = fmaxf((area1 + s_area2[(J)]) - INTER, 1e-10f);           \
    }

#define STEP(BI, BU, BX, INTER, UM, J)                                \
    {                                                                 \
        const float p1 = (INTER) * (BU);                              \
        const float p2 = (BI) * (UM);                                 \
        const float p2p = p2 * ONE_P;                                 \
        const float p2m = p2 * ONE_M;                                 \
        const bool upd = p1 > p2p;                                    \
        slow = slow | (((INTER) > 0.0f) & (p1 >= p2m) & (p1 <= p2p)); \
        if (upd) { BI = (INTER); BU = (UM); BX = (J); }               \
    }

#pragma unroll 4
    for (int j = 0; j < 64; ++j) {
        {
            float inter, um;
            FRAC(j, inter, um)
            STEP(biA, buA, bxA, inter, um, j)
        }
        {
            float inter, um;
            FRAC(j + 64, inter, um)
            STEP(biB, buB, bxB, inter, um, j + 64)
        }
    }

    // merge stream B (later indices) into A (earlier) — tie keeps A
    {
        const float p1 = biB * buA;
        const float p2 = biA * buB;
        const float p2p = p2 * ONE_P;
        const float p2m = p2 * ONE_M;
        const bool upd = p1 > p2p;
        slow = slow | ((biB > 0.0f) & (p1 >= p2m) & (p1 <= p2p));
        if (upd) { biA = biB; buA = buB; bxA = bxB; }
    }

    // single exact IEEE divide reproduces reference matched_val bitwise
    float d = biA / buA;
    int xi = bxA;

    if (slow) {
        // near-tie detected: replay with the reference's exact semantics
        float best = -1.0f;
        int bidx = 0;
        for (int j = 0; j < N2; ++j) {
            float inter, um;
            FRAC(j, inter, um)
            const float q = inter / um;
            if (q > best) { best = q; bidx = j; }
        }
        d = best;
        xi = bidx;
    }

    out_vals[i]   = d;
    out_idx[i]    = (float)xi;
    out_labels[i] = (d >= 0.7f) ? 1.0f : ((d < 0.3f) ? 0.0f : -1.0f);
}

extern "C" void kernel_launch(void* const* d_in, const int* in_sizes, int n_in,
                              void* d_out, int out_size, void* d_ws, size_t ws_size,
                              hipStream_t stream) {
    const float4* boxes1 = (const float4*)d_in[0];
    const float4* boxes2 = (const float4*)d_in[1];
    const int n1 = in_sizes[0] / 4;

    float* out = (float*)d_out;
    float* out_vals   = out;
    float* out_idx    = out + n1;
    float* out_labels = out + 2 * n1;

    const int grid = (n1 + BLOCK - 1) / BLOCK;
    matcher_kernel<<<grid, BLOCK, 0, stream>>>(boxes1, boxes2,
                                               out_vals, out_idx, out_labels, n1);
}

// Round 3
// 29.024 us; speedup vs baseline: 1.3865x; 1.3865x over previous
//
#include <hip/hip_runtime.h>

#define N2 128
#define BLOCK 256        // 4 waves; wave w covers j in [32w, 32w+32)
#define APB 64           // anchors per block (one per lane)

__global__ __launch_bounds__(BLOCK, 8) void matcher_kernel(
    const float4* __restrict__ boxes1,
    const float4* __restrict__ boxes2,
    float* __restrict__ out_vals,
    float* __restrict__ out_idx,
    float* __restrict__ out_labels,
    int n1)
{
#pragma clang fp contract(off)
    __shared__ float s_area2[N2];
    __shared__ float s_q[4][APB];
    __shared__ int   s_ix[4][APB];

    const int t = threadIdx.x;
    if (t < N2) {
        const float4 b = boxes2[t];            // (y1, x1, y2, x2)
        s_area2[t] = (b.z - b.x) * (b.w - b.y);
    }
    __syncthreads();

    const int w    = __builtin_amdgcn_readfirstlane(t >> 6); // wave id, uniform
    const int lane = t & 63;
    const int i    = blockIdx.x * APB + lane;
    const bool valid = (i < n1);

    // out-of-range lanes just compute garbage on box 0; they don't write
    const float4 a = boxes1[valid ? i : 0];
    const float area1 = (a.z - a.x) * (a.w - a.y);

    float best = -1.0f;      // first candidate always wins (matches ref)
    int   bidx = 0;

    const int j0 = w * 32;
#pragma unroll 8
    for (int k = 0; k < 32; ++k) {
        const int j = j0 + k;                  // wave-uniform index
        const float4 b = boxes2[j];            // uniform -> scalar load / L1 broadcast
        const float a2 = s_area2[j];           // uniform -> LDS broadcast, no conflict
        const float iy1 = fmaxf(a.x, b.x);
        const float ix1 = fmaxf(a.y, b.y);
        const float iy2 = fminf(a.z, b.z);
        const float ix2 = fminf(a.w, b.w);
        const float hy = fmaxf(iy2 - iy1, 0.0f);
        const float hx = fmaxf(ix2 - ix1, 0.0f);
        const float inter = hy * hx;
        const float uni = (area1 + a2) - inter;      // ref op order
        const float q = inter / fmaxf(uni, 1e-10f);  // exact IEEE divide
        if (q > best) { best = q; bidx = j; }        // strict >, ascending j
    }

    s_q[w][lane]  = best;
    s_ix[w][lane] = bidx;
    __syncthreads();

    // merge the 4 wave-partials; ascending wave + strict > == first-max
    if (t < APB) {
        const int ii = blockIdx.x * APB + t;
        if (ii < n1) {
            float q  = s_q[0][t];
            int   ix = s_ix[0][t];
#pragma unroll
            for (int w2 = 1; w2 < 4; ++w2) {
                const float q2 = s_q[w2][t];
                if (q2 > q) { q = q2; ix = s_ix[w2][t]; }
            }
            out_vals[ii]   = q;
            out_idx[ii]    = (float)ix;
            out_labels[ii] = (q >= 0.7f) ? 1.0f : ((q < 0.3f) ? 0.0f : -1.0f);
        }
    }
}

extern "C" void kernel_launch(void* const* d_in, const int* in_sizes, int n_in,
                              void* d_out, int out_size, void* d_ws, size_t ws_size,
                              hipStream_t stream) {
    const float4* boxes1 = (const float4*)d_in[0];
    const float4* boxes2 = (const float4*)d_in[1];
    const int n1 = in_sizes[0] / 4;

    float* out = (float*)d_out;
    float* out_vals   = out;
    float* out_idx    = out + n1;
    float* out_labels = out + 2 * n1;

    const int grid = (n1 + APB - 1) / APB;
    matcher_kernel<<<grid, BLOCK, 0, stream>>>(boxes1, boxes2,
                                               out_vals, out_idx, out_labels, n1);
}

// Round 4
// 28.410 us; speedup vs baseline: 1.4165x; 1.0216x over previous
//
#include <hip/hip_runtime.h>

#define N2 128
#define BLOCK 256        // 4 waves; wave w covers j in [32w, 32w+32)
#define APB 64           // anchors per block (one per lane)
#define BAND 9.5367431640625e-07f   // 2^-20 relative guard band

__global__ __launch_bounds__(BLOCK, 8) void matcher_kernel(
    const float4* __restrict__ boxes1,
    const float4* __restrict__ boxes2,
    float* __restrict__ out_vals,
    float* __restrict__ out_idx,
    float* __restrict__ out_labels,
    int n1)
{
#pragma clang fp contract(off)
    __shared__ float4 s_b2[N2];
    __shared__ float  s_area2[N2];
    __shared__ float  s_q[4][APB];
    __shared__ int    s_ix[4][APB];

    const int t = threadIdx.x;
    if (t < N2) {
        const float4 b = boxes2[t];            // (y1, x1, y2, x2)
        s_b2[t] = b;
        s_area2[t] = (b.z - b.x) * (b.w - b.y);
    }
    __syncthreads();

    const int w    = __builtin_amdgcn_readfirstlane(t >> 6); // wave id, uniform
    const int lane = t & 63;
    const int i    = blockIdx.x * APB + lane;
    const bool valid = (i < n1);

    const float4 a = boxes1[valid ? i : 0];
    const float area1 = (a.z - a.x) * (a.w - a.y);

#define FRAC(J, INTER, UM)                                            \
    {                                                                 \
        const float4 b = s_b2[(J)];                                   \
        const float iy1 = fmaxf(a.x, b.x);                            \
        const float ix1 = fmaxf(a.y, b.y);                            \
        const float iy2 = fminf(a.z, b.z);                            \
        const float ix2 = fminf(a.w, b.w);                            \
        const float hy = fmaxf(iy2 - iy1, 0.0f);                      \
        const float hx = fmaxf(ix2 - ix1, 0.0f);                      \
        INTER = hy * hx;                                              \
        UM = fmaxf((area1 + s_area2[(J)]) - INTER, 1e-10f);           \
    }

    const int j0 = w * 32;
    float bq = -1.0f;          // approx best quotient; first candidate wins
    int   bidx = j0;
    bool  slow = false;

#pragma unroll 8
    for (int k = 0; k < 32; ++k) {
        const int j = j0 + k;                  // wave-uniform index
        const float4 b = boxes2[j];            // uniform -> scalar load
        const float a2 = s_area2[j];           // uniform -> LDS broadcast
        const float iy1 = fmaxf(a.x, b.x);
        const float ix1 = fmaxf(a.y, b.y);
        const float iy2 = fminf(a.z, b.z);
        const float ix2 = fminf(a.w, b.w);
        const float hy = fmaxf(iy2 - iy1, 0.0f);
        const float hx = fmaxf(ix2 - ix1, 0.0f);
        const float inter = hy * hx;
        const float um = fmaxf((area1 + a2) - inter, 1e-10f);
        // fast approx quotient: no VCC, no denorm-mode toggles, 1 rcp + 1 mul
        const float q   = inter * __builtin_amdgcn_rcpf(um);
        const float dlt = q - bq;
        const float thr = bq * BAND;
        // near-tie between two POSITIVE quotients -> can't trust approx order
        slow = slow | ((inter > 0.0f) & (fabsf(dlt) <= thr));
        if (dlt > thr) { bq = q; bidx = j; }
    }

    if (slow) {
        // exact replay of this wave's window with reference semantics
        float best = -1.0f;
        int   bx = j0;
        for (int k = 0; k < 32; ++k) {
            const int j = j0 + k;
            float inter, um;
            FRAC(j, inter, um)
            const float qq = inter / um;       // exact IEEE divide
            if (qq > best) { best = qq; bx = j; }
        }
        bidx = bx;
    }

    // one exact IEEE divide on the winner reproduces matched_val bitwise
    float qe;
    {
        float inter, um;
        FRAC(bidx, inter, um)                  // per-lane LDS gather, once
        qe = inter / um;
    }

    s_q[w][lane]  = qe;
    s_ix[w][lane] = bidx;
    __syncthreads();

    // merge the 4 wave-partials; ascending wave + strict > == first-max
    if (t < APB) {
        const int ii = blockIdx.x * APB + t;
        if (ii < n1) {
            float q  = s_q[0][t];
            int   ix = s_ix[0][t];
#pragma unroll
            for (int w2 = 1; w2 < 4; ++w2) {
                const float q2 = s_q[w2][t];
                if (q2 > q) { q = q2; ix = s_ix[w2][t]; }
            }
            out_vals[ii]   = q;
            out_idx[ii]    = (float)ix;
            out_labels[ii] = (q >= 0.7f) ? 1.0f : ((q < 0.3f) ? 0.0f : -1.0f);
        }
    }
}

extern "C" void kernel_launch(void* const* d_in, const int* in_sizes, int n_in,
                              void* d_out, int out_size, void* d_ws, size_t ws_size,
                              hipStream_t stream) {
    const float4* boxes1 = (const float4*)d_in[0];
    const float4* boxes2 = (const float4*)d_in[1];
    const int n1 = in_sizes[0] / 4;

    float* out = (float*)d_out;
    float* out_vals   = out;
    float* out_idx    = out + n1;
    float* out_labels = out + 2 * n1;

    const int grid = (n1 + APB - 1) / APB;
    matcher_kernel<<<grid, BLOCK, 0, stream>>>(boxes1, boxes2,
                                               out_vals, out_idx, out_labels, n1);
}